// Round 1
// baseline (805.511 us; speedup 1.0000x reference)
//
#include <hip/hip_runtime.h>
#include <math.h>

// ---------------- graph preprocessing ----------------

__global__ void k_hist(const int* dst, int* deg, int E) {
    int e = blockIdx.x * blockDim.x + threadIdx.x;
    if (e < E) atomicAdd(&deg[dst[e]], 1);
}

// 256 threads x 8 items = 2048 per block. Writes inclusive scan of deg[0..N-1]
// into out1[0..N-1] (== rowptr+1), chunk totals into partials.
__global__ void k_scan_a(const int* deg, int* out1, int* partials, int N) {
    __shared__ int sd[256];
    int t = threadIdx.x;
    int base = blockIdx.x * 2048 + t * 8;
    int v[8];
    int s = 0;
#pragma unroll
    for (int j = 0; j < 8; j++) {
        int idx = base + j;
        int d = (idx < N) ? deg[idx] : 0;
        s += d;
        v[j] = s;
    }
    sd[t] = s;
    __syncthreads();
    for (int off = 1; off < 256; off <<= 1) {
        int add = (t >= off) ? sd[t - off] : 0;
        __syncthreads();
        sd[t] += add;
        __syncthreads();
    }
    int excl = sd[t] - s;
#pragma unroll
    for (int j = 0; j < 8; j++) {
        int idx = base + j;
        if (idx < N) out1[idx] = excl + v[j];
    }
    if (t == 255) partials[blockIdx.x] = sd[255];
}

__global__ void k_scan_b(int* partials, int nb) {
    if (threadIdx.x == 0 && blockIdx.x == 0) {
        int s = 0;
        for (int i = 0; i < nb; i++) { s += partials[i]; partials[i] = s; }
    }
}

__global__ void k_scan_c(int* rowptr, const int* partials, int N) {
    int i = blockIdx.x * blockDim.x + threadIdx.x;
    if (i == 0) rowptr[0] = 0;
    if (i < N) {
        int blk = i / 2048;
        if (blk > 0) rowptr[1 + i] += partials[blk - 1];
    }
}

// pack = (rel<<17) | src   (src < 2^17, rel < 8)
__global__ void k_scatter(const int* src, const int* dst, const int* et,
                          int* cursor, int* csr, int E) {
    int e = blockIdx.x * blockDim.x + threadIdx.x;
    if (e < E) {
        int d = dst[e];
        int slot = atomicAdd(&cursor[d], 1);
        csr[slot] = (et[e] << 17) | src[e];
    }
}

// ---------------- per-layer kernels ----------------

// wq[r*64+i] = sum_o W[r,i,o]*Qv[o]; wk likewise.
__global__ void k_wqk(const float* W, const float* Qv, const float* Kv,
                      float* wq, float* wk, int OUT) {
    int t = blockIdx.x * blockDim.x + threadIdx.x;  // r*64 + i
    if (t < 8 * 64) {
        int r = t >> 6, i = t & 63;
        const float* wrow = W + ((size_t)r * 64 + i) * OUT;
        float a = 0.f, b = 0.f;
        for (int o = 0; o < OUT; o++) {
            float w = wrow[o];
            a += w * Qv[o];
            b += w * Kv[o];
        }
        wq[t] = a;
        wk[t] = b;
    }
}

// qn[n*8+r] = sum_i xin[n,i]*wq[r,i]; kn likewise. IN fixed at 64.
__global__ void k_qk(const float* xin, const float* wq, const float* wk,
                     float* qn, float* kn, int N) {
    __shared__ float sq[8 * 65], sk[8 * 65];
    int t = threadIdx.x;
    for (int idx = t; idx < 8 * 64; idx += blockDim.x) {
        int r = idx >> 6, i = idx & 63;
        sq[r * 65 + i] = wq[idx];
        sk[r * 65 + i] = wk[idx];
    }
    __syncthreads();
    int g = blockIdx.x * blockDim.x + t;
    if (g < N * 8) {
        int n = g >> 3, r = g & 7;
        const float* xp = xin + (size_t)n * 64;
        float qa = 0.f, ka = 0.f;
#pragma unroll
        for (int i = 0; i < 64; i++) {
            float xv = xp[i];
            qa += xv * sq[r * 65 + i];
            ka += xv * sk[r * 65 + i];
        }
        qn[g] = qa;
        kn[g] = ka;
    }
}

// xw[r,n,o] = sum_i xin[n,i] * W[r,i,o].  IN = 64.
template <int OUT>
__global__ void k_xw(const float* xin, const float* W, float* xw, int N) {
    constexpr int TPN = OUT / 4;   // threads per node (one float4 of outputs each)
    constexpr int NT = 256 / TPN;  // nodes per block
    __shared__ float wl[64 * OUT];
    __shared__ float xt[NT * 65];
    int t = threadIdx.x;
    int r = blockIdx.y;
    const float* Wr = W + (size_t)r * 64 * OUT;
    for (int idx = t; idx < 64 * OUT; idx += 256) wl[idx] = Wr[idx];
    int nb0 = blockIdx.x * NT;
    for (int idx = t; idx < NT * 64; idx += 256) {
        int ns = idx >> 6, i = idx & 63;
        int n = nb0 + ns;
        xt[ns * 65 + i] = (n < N) ? xin[(size_t)n * 64 + i] : 0.f;
    }
    __syncthreads();
    int ns = t / TPN;
    int o0 = (t % TPN) * 4;
    int n = nb0 + ns;
    if (n < N) {
        float a0 = 0.f, a1 = 0.f, a2 = 0.f, a3 = 0.f;
#pragma unroll
        for (int i = 0; i < 64; i++) {
            float xv = xt[ns * 65 + i];
            const float* w4 = &wl[i * OUT + o0];
            a0 += xv * w4[0];
            a1 += xv * w4[1];
            a2 += xv * w4[2];
            a3 += xv * w4[3];
        }
        float4 res = {a0, a1, a2, a3};
        *(float4*)(xw + ((size_t)r * N + n) * OUT + o0) = res;
    }
}

// One wave per dst node: edge-parallel softmax stats, per-edge gather-accumulate.
template <int OUT, bool RELU>
__global__ void k_agg(const int* __restrict__ rowptr, const int* __restrict__ csr,
                      const float* __restrict__ qn, const float* __restrict__ kn,
                      const float* __restrict__ xw, const float* __restrict__ bias,
                      float* __restrict__ xout, int N) {
    int wid = (blockIdx.x * blockDim.x + threadIdx.x) >> 6;
    int lane = threadIdx.x & 63;
    if (wid >= N) return;
    int n = wid;
    int r0 = rowptr[n], r1 = rowptr[n + 1];

    // pass 1: max over incoming-edge logits
    float m = -INFINITY;
    for (int base = r0; base < r1; base += 64) {
        int s = base + lane;
        float a = -INFINITY;
        if (s < r1) {
            int pk = csr[s];
            int src = pk & 0x1FFFF;
            int rel = pk >> 17;
            float v = qn[n * 8 + rel] + kn[src * 8 + rel];
            a = (v >= 0.f) ? v : 0.2f * v;
        }
#pragma unroll
        for (int off = 32; off > 0; off >>= 1) a = fmaxf(a, __shfl_xor(a, off, 64));
        m = fmaxf(m, a);
    }

    // pass 2: exp-sum + unnormalized weighted aggregation of xw[rel,src,:]
    float denom = 0.f;
    float acc = 0.f;
    for (int base = r0; base < r1; base += 64) {
        int s = base + lane;
        float tv = 0.f;
        int pk = 0;
        if (s < r1) {
            pk = csr[s];
            int src = pk & 0x1FFFF;
            int rel = pk >> 17;
            float v = qn[n * 8 + rel] + kn[src * 8 + rel];
            v = (v >= 0.f) ? v : 0.2f * v;
            tv = __expf(v - m);
        }
        float ts = tv;
#pragma unroll
        for (int off = 32; off > 0; off >>= 1) ts += __shfl_xor(ts, off, 64);
        denom += ts;
        int cnt = min(64, r1 - base);
        for (int j = 0; j < cnt; j++) {
            float tj = __shfl(tv, j, 64);
            int pkj = __shfl(pk, j, 64);
            int srcj = pkj & 0x1FFFF;
            int relj = pkj >> 17;
            const float* xp = xw + ((size_t)relj * N + srcj) * OUT;
            if (lane < OUT) acc += tj * xp[lane];
        }
    }

    if (lane < OUT) {
        float o = acc / (denom + 1e-16f) + bias[lane];
        if (RELU) o = fmaxf(o, 0.f);
        xout[(size_t)n * OUT + lane] = o;
    }
}

// ---------------- host launch ----------------

extern "C" void kernel_launch(void* const* d_in, const int* in_sizes, int n_in,
                              void* d_out, int out_size, void* d_ws, size_t ws_size,
                              hipStream_t stream) {
    const float* x   = (const float*)d_in[0];
    const int*   ei  = (const int*)d_in[1];
    const int*   et  = (const int*)d_in[2];
    const float* W0  = (const float*)d_in[3];
    const float* Q0  = (const float*)d_in[4];
    const float* K0  = (const float*)d_in[5];
    const float* b0  = (const float*)d_in[6];
    const float* W1  = (const float*)d_in[7];
    const float* Q1  = (const float*)d_in[8];
    const float* K1  = (const float*)d_in[9];
    const float* b1  = (const float*)d_in[10];
    float* out = (float*)d_out;

    const int N = in_sizes[0] / 64;
    const int E = in_sizes[2];
    const int* src = ei;
    const int* dst = ei + E;

    // workspace carve (256B aligned)
    char* p = (char*)d_ws;
    auto alloc = [&](size_t bytes) -> void* {
        void* r = (void*)p;
        p += ((bytes + 255) / 256) * 256;
        return r;
    };
    int* rowptr   = (int*)alloc((size_t)(N + 1) * 4);
    int* cursor   = (int*)alloc((size_t)(N + 1) * 4);
    int* deg      = (int*)alloc((size_t)N * 4);
    int* partials = (int*)alloc(256 * 4);
    int* csr      = (int*)alloc((size_t)E * 4);
    float* wq     = (float*)alloc(8 * 64 * 4);
    float* wk     = (float*)alloc(8 * 64 * 4);
    float* qn     = (float*)alloc((size_t)N * 8 * 4);
    float* kn     = (float*)alloc((size_t)N * 8 * 4);
    float* xw     = (float*)alloc((size_t)8 * N * 64 * 4);
    float* h      = (float*)alloc((size_t)N * 64 * 4);

    // --- CSR build (shared by both layers) ---
    hipMemsetAsync(deg, 0, (size_t)N * 4, stream);
    k_hist<<<(E + 255) / 256, 256, 0, stream>>>(dst, deg, E);
    int nb = (N + 2047) / 2048;
    k_scan_a<<<nb, 256, 0, stream>>>(deg, rowptr + 1, partials, N);
    k_scan_b<<<1, 64, 0, stream>>>(partials, nb);
    k_scan_c<<<(N + 255) / 256, 256, 0, stream>>>(rowptr, partials, N);
    hipMemcpyAsync(cursor, rowptr, (size_t)(N + 1) * 4, hipMemcpyDeviceToDevice, stream);
    k_scatter<<<(E + 255) / 256, 256, 0, stream>>>(src, dst, et, cursor, csr, E);

    // --- layer 0: 64 -> 64, relu ---
    k_wqk<<<2, 256, 0, stream>>>(W0, Q0, K0, wq, wk, 64);
    k_qk<<<(N * 8 + 255) / 256, 256, 0, stream>>>(x, wq, wk, qn, kn, N);
    k_xw<64><<<dim3((N + 15) / 16, 8), 256, 0, stream>>>(x, W0, xw, N);
    k_agg<64, true><<<(N * 64 + 255) / 256, 256, 0, stream>>>(rowptr, csr, qn, kn, xw, b0, h, N);

    // --- layer 1: 64 -> 32, no relu ---
    k_wqk<<<2, 256, 0, stream>>>(W1, Q1, K1, wq, wk, 32);
    k_qk<<<(N * 8 + 255) / 256, 256, 0, stream>>>(h, wq, wk, qn, kn, N);
    k_xw<32><<<dim3((N + 31) / 32, 8), 256, 0, stream>>>(h, W1, xw, N);
    k_agg<32, false><<<(N * 64 + 255) / 256, 256, 0, stream>>>(rowptr, csr, qn, kn, xw, b1, out, N);
}

// Round 2
// 760.136 us; speedup vs baseline: 1.0597x; 1.0597x over previous
//
#include <hip/hip_runtime.h>
#include <math.h>

// ---------------- graph preprocessing ----------------

__global__ void k_hist(const int* dst, int* deg, int E) {
    int e = blockIdx.x * blockDim.x + threadIdx.x;
    if (e < E) atomicAdd(&deg[dst[e]], 1);
}

// 256 threads x 8 items = 2048 per block. Writes inclusive scan of deg[0..N-1]
// into out1[0..N-1] (== rowptr+1), chunk totals into partials.
__global__ void k_scan_a(const int* deg, int* out1, int* partials, int N) {
    __shared__ int sd[256];
    int t = threadIdx.x;
    int base = blockIdx.x * 2048 + t * 8;
    int v[8];
    int s = 0;
#pragma unroll
    for (int j = 0; j < 8; j++) {
        int idx = base + j;
        int d = (idx < N) ? deg[idx] : 0;
        s += d;
        v[j] = s;
    }
    sd[t] = s;
    __syncthreads();
    for (int off = 1; off < 256; off <<= 1) {
        int add = (t >= off) ? sd[t - off] : 0;
        __syncthreads();
        sd[t] += add;
        __syncthreads();
    }
    int excl = sd[t] - s;
#pragma unroll
    for (int j = 0; j < 8; j++) {
        int idx = base + j;
        if (idx < N) out1[idx] = excl + v[j];
    }
    if (t == 255) partials[blockIdx.x] = sd[255];
}

__global__ void k_scan_b(int* partials, int nb) {
    if (threadIdx.x == 0 && blockIdx.x == 0) {
        int s = 0;
        for (int i = 0; i < nb; i++) { s += partials[i]; partials[i] = s; }
    }
}

__global__ void k_scan_c(int* rowptr, const int* partials, int N) {
    int i = blockIdx.x * blockDim.x + threadIdx.x;
    if (i == 0) rowptr[0] = 0;
    if (i < N) {
        int blk = i / 2048;
        if (blk > 0) rowptr[1 + i] += partials[blk - 1];
    }
}

// pack = (rel<<17) | src   (src < 2^17, rel < 8)
__global__ void k_scatter(const int* src, const int* dst, const int* et,
                          int* cursor, int* csr, int E) {
    int e = blockIdx.x * blockDim.x + threadIdx.x;
    if (e < E) {
        int d = dst[e];
        int slot = atomicAdd(&cursor[d], 1);
        csr[slot] = (et[e] << 17) | src[e];
    }
}

// ---------------- per-layer kernels ----------------

// Fused relation-transform + attention projections.
// Block: 256 threads = 64 nodes x 4 wave-groups (h = t>>6).
// Each thread: node ns, relations {2h, 2h+1}, all OUT outputs.
// W is wave-uniform -> scalar (SGPR/K$) path; x per-lane from LDS (65-pad,
// 2-way bank alias = free). Inner loop: 16 v_fma per 1 ds_read_b32.
// Also emits qn[n*8+r] = xw[r,n,:].Q and kn likewise (fuses old k_qk).
template <int OUT>
__global__ __launch_bounds__(256, 4) void k_xw2(
        const float* __restrict__ xin, const float* __restrict__ W,
        const float* __restrict__ Qv, const float* __restrict__ Kv,
        float* __restrict__ xw, float* __restrict__ qn, float* __restrict__ kn,
        int N) {
    __shared__ float xt[64 * 65];
    int t = threadIdx.x;
    int nb0 = blockIdx.x * 64;
    for (int idx = t; idx < 64 * 64; idx += 256) {
        int ns = idx >> 6, i = idx & 63;
        int n = nb0 + ns;
        xt[ns * 65 + i] = (n < N) ? xin[(size_t)n * 64 + i] : 0.f;
    }
    __syncthreads();
    int ns = t & 63;
    int h = __builtin_amdgcn_readfirstlane(t >> 6);  // 0..3, wave-uniform
    int gn = nb0 + ns;
    const float* xrow = &xt[ns * 65];

    for (int rl = 0; rl < 2; rl++) {
        int rr = h * 2 + rl;
        const float* Wr = W + (size_t)rr * 64 * OUT;
        float qacc = 0.f, kacc = 0.f;
        float* xwrow = xw + ((size_t)rr * N + gn) * OUT;
        for (int oc = 0; oc < OUT; oc += 16) {
            float acc[16];
#pragma unroll
            for (int o = 0; o < 16; o++) acc[o] = 0.f;
            const float* wbase = Wr + oc;
            for (int i = 0; i < 64; i++) {
                float xv = xrow[i];
                const float* w = wbase + i * OUT;  // wave-uniform -> s_load
#pragma unroll
                for (int o = 0; o < 16; o++) acc[o] += xv * w[o];
            }
#pragma unroll
            for (int o = 0; o < 16; o++) {
                qacc += acc[o] * Qv[oc + o];
                kacc += acc[o] * Kv[oc + o];
            }
            if (gn < N) {
#pragma unroll
                for (int j = 0; j < 4; j++) {
                    float4 res = {acc[4 * j], acc[4 * j + 1],
                                  acc[4 * j + 2], acc[4 * j + 3]};
                    *(float4*)(xwrow + oc + 4 * j) = res;
                }
            }
        }
        if (gn < N) {
            qn[gn * 8 + rr] = qacc;
            kn[gn * 8 + rr] = kacc;
        }
    }
}

// One wave per dst node: edge-parallel softmax stats, per-edge gather-accumulate.
template <int OUT, bool RELU>
__global__ void k_agg(const int* __restrict__ rowptr, const int* __restrict__ csr,
                      const float* __restrict__ qn, const float* __restrict__ kn,
                      const float* __restrict__ xw, const float* __restrict__ bias,
                      float* __restrict__ xout, int N) {
    int wid = (blockIdx.x * blockDim.x + threadIdx.x) >> 6;
    int lane = threadIdx.x & 63;
    if (wid >= N) return;
    int n = wid;
    int r0 = rowptr[n], r1 = rowptr[n + 1];

    // pass 1: max over incoming-edge logits
    float m = -INFINITY;
    for (int base = r0; base < r1; base += 64) {
        int s = base + lane;
        float a = -INFINITY;
        if (s < r1) {
            int pk = csr[s];
            int src = pk & 0x1FFFF;
            int rel = pk >> 17;
            float v = qn[n * 8 + rel] + kn[src * 8 + rel];
            a = (v >= 0.f) ? v : 0.2f * v;
        }
#pragma unroll
        for (int off = 32; off > 0; off >>= 1) a = fmaxf(a, __shfl_xor(a, off, 64));
        m = fmaxf(m, a);
    }

    // pass 2: exp-sum + unnormalized weighted aggregation of xw[rel,src,:]
    float denom = 0.f;
    float acc = 0.f;
    for (int base = r0; base < r1; base += 64) {
        int s = base + lane;
        float tv = 0.f;
        int pk = 0;
        if (s < r1) {
            pk = csr[s];
            int src = pk & 0x1FFFF;
            int rel = pk >> 17;
            float v = qn[n * 8 + rel] + kn[src * 8 + rel];
            v = (v >= 0.f) ? v : 0.2f * v;
            tv = __expf(v - m);
        }
        float ts = tv;
#pragma unroll
        for (int off = 32; off > 0; off >>= 1) ts += __shfl_xor(ts, off, 64);
        denom += ts;
        int cnt = min(64, r1 - base);
        for (int j = 0; j < cnt; j++) {
            float tj = __shfl(tv, j, 64);
            int pkj = __shfl(pk, j, 64);
            int srcj = pkj & 0x1FFFF;
            int relj = pkj >> 17;
            const float* xp = xw + ((size_t)relj * N + srcj) * OUT;
            if (lane < OUT) acc += tj * xp[lane];
        }
    }

    if (lane < OUT) {
        float o = acc / (denom + 1e-16f) + bias[lane];
        if (RELU) o = fmaxf(o, 0.f);
        xout[(size_t)n * OUT + lane] = o;
    }
}

// ---------------- host launch ----------------

extern "C" void kernel_launch(void* const* d_in, const int* in_sizes, int n_in,
                              void* d_out, int out_size, void* d_ws, size_t ws_size,
                              hipStream_t stream) {
    const float* x   = (const float*)d_in[0];
    const int*   ei  = (const int*)d_in[1];
    const int*   et  = (const int*)d_in[2];
    const float* W0  = (const float*)d_in[3];
    const float* Q0  = (const float*)d_in[4];
    const float* K0  = (const float*)d_in[5];
    const float* b0  = (const float*)d_in[6];
    const float* W1  = (const float*)d_in[7];
    const float* Q1  = (const float*)d_in[8];
    const float* K1  = (const float*)d_in[9];
    const float* b1  = (const float*)d_in[10];
    float* out = (float*)d_out;

    const int N = in_sizes[0] / 64;
    const int E = in_sizes[2];
    const int* src = ei;
    const int* dst = ei + E;

    // workspace carve (256B aligned)
    char* p = (char*)d_ws;
    auto alloc = [&](size_t bytes) -> void* {
        void* r = (void*)p;
        p += ((bytes + 255) / 256) * 256;
        return r;
    };
    int* rowptr   = (int*)alloc((size_t)(N + 1) * 4);
    int* cursor   = (int*)alloc((size_t)(N + 1) * 4);
    int* deg      = (int*)alloc((size_t)N * 4);
    int* partials = (int*)alloc(256 * 4);
    int* csr      = (int*)alloc((size_t)E * 4);
    float* qn     = (float*)alloc((size_t)N * 8 * 4);
    float* kn     = (float*)alloc((size_t)N * 8 * 4);
    float* xw     = (float*)alloc((size_t)8 * N * 64 * 4);
    float* h      = (float*)alloc((size_t)N * 64 * 4);

    // --- CSR build (shared by both layers) ---
    hipMemsetAsync(deg, 0, (size_t)N * 4, stream);
    k_hist<<<(E + 255) / 256, 256, 0, stream>>>(dst, deg, E);
    int nb = (N + 2047) / 2048;
    k_scan_a<<<nb, 256, 0, stream>>>(deg, rowptr + 1, partials, N);
    k_scan_b<<<1, 64, 0, stream>>>(partials, nb);
    k_scan_c<<<(N + 255) / 256, 256, 0, stream>>>(rowptr, partials, N);
    hipMemcpyAsync(cursor, rowptr, (size_t)(N + 1) * 4, hipMemcpyDeviceToDevice, stream);
    k_scatter<<<(E + 255) / 256, 256, 0, stream>>>(src, dst, et, cursor, csr, E);

    int nxb = (N + 63) / 64;

    // --- layer 0: 64 -> 64, relu ---
    k_xw2<64><<<nxb, 256, 0, stream>>>(x, W0, Q0, K0, xw, qn, kn, N);
    k_agg<64, true><<<(N * 64 + 255) / 256, 256, 0, stream>>>(rowptr, csr, qn, kn, xw, b0, h, N);

    // --- layer 1: 64 -> 32, no relu ---
    k_xw2<32><<<nxb, 256, 0, stream>>>(h, W1, Q1, K1, xw, qn, kn, N);
    k_agg<32, false><<<(N * 64 + 255) / 256, 256, 0, stream>>>(rowptr, csr, qn, kn, xw, b1, out, N);
}

// Round 5
// 725.315 us; speedup vs baseline: 1.1106x; 1.0480x over previous
//
#include <hip/hip_runtime.h>
#include <hip/hip_bf16.h>
#include <math.h>

// ---------------- graph preprocessing ----------------

__global__ void k_hist(const int* dst, int* deg, int E) {
    int e = blockIdx.x * blockDim.x + threadIdx.x;
    if (e < E) atomicAdd(&deg[dst[e]], 1);
}

__global__ void k_scan_a(const int* deg, int* out1, int* partials, int N) {
    __shared__ int sd[256];
    int t = threadIdx.x;
    int base = blockIdx.x * 2048 + t * 8;
    int v[8];
    int s = 0;
#pragma unroll
    for (int j = 0; j < 8; j++) {
        int idx = base + j;
        int d = (idx < N) ? deg[idx] : 0;
        s += d;
        v[j] = s;
    }
    sd[t] = s;
    __syncthreads();
    for (int off = 1; off < 256; off <<= 1) {
        int add = (t >= off) ? sd[t - off] : 0;
        __syncthreads();
        sd[t] += add;
        __syncthreads();
    }
    int excl = sd[t] - s;
#pragma unroll
    for (int j = 0; j < 8; j++) {
        int idx = base + j;
        if (idx < N) out1[idx] = excl + v[j];
    }
    if (t == 255) partials[blockIdx.x] = sd[255];
}

__global__ void k_scan_b(int* partials, int nb) {
    if (threadIdx.x == 0 && blockIdx.x == 0) {
        int s = 0;
        for (int i = 0; i < nb; i++) { s += partials[i]; partials[i] = s; }
    }
}

__global__ void k_scan_c(int* rowptr, const int* partials, int N) {
    int i = blockIdx.x * blockDim.x + threadIdx.x;
    if (i == 0) rowptr[0] = 0;
    if (i < N) {
        int blk = i / 2048;
        if (blk > 0) rowptr[1 + i] += partials[blk - 1];
    }
}

// pack = (rel<<17) | src   (src < 2^17, rel < 8)
__global__ void k_scatter(const int* src, const int* dst, const int* et,
                          int* cursor, int* csr, int E) {
    int e = blockIdx.x * blockDim.x + threadIdx.x;
    if (e < E) {
        int d = dst[e];
        int slot = atomicAdd(&cursor[d], 1);
        csr[slot] = (et[e] << 17) | src[e];
    }
}

// ---------------- weight prep ----------------

// Split-transpose: Wt_hi[r][o][i] = bf16(W[r][i][o]); Wt_lo = bf16(residual).
__global__ void k_wt(const float* __restrict__ W, __hip_bfloat16* __restrict__ Wthi,
                     __hip_bfloat16* __restrict__ Wtlo, int OUT, int total) {
    int t = blockIdx.x * blockDim.x + threadIdx.x;
    if (t < total) {
        int per = 64 * OUT;
        int r = t / per;
        int rem = t % per;
        int i = rem / OUT;
        int o = rem % OUT;
        float v = W[t];
        __hip_bfloat16 hi = __float2bfloat16(v);
        __hip_bfloat16 lo = __float2bfloat16(v - __bfloat162float(hi));
        size_t idx = ((size_t)r * OUT + o) * 64 + i;
        Wthi[idx] = hi;
        Wtlo[idx] = lo;
    }
}

// wq[r*64+i] = sum_o W[r,i,o]*Qv[o]; wk likewise. (fp32, tiny)
__global__ void k_wqk(const float* W, const float* Qv, const float* Kv,
                      float* wq, float* wk, int OUT) {
    int t = blockIdx.x * blockDim.x + threadIdx.x;
    if (t < 8 * 64) {
        int r = t >> 6, i = t & 63;
        const float* wrow = W + ((size_t)r * 64 + i) * OUT;
        float a = 0.f, b = 0.f;
        for (int o = 0; o < OUT; o++) {
            float w = wrow[o];
            a += w * Qv[o];
            b += w * Kv[o];
        }
        wq[t] = a;
        wk[t] = b;
    }
}

// qn[n*8+r] = sum_i xin[n,i]*wq[r,i]; kn likewise. IN fixed at 64. (fp32)
__global__ void k_qk(const float* __restrict__ xin, const float* __restrict__ wq,
                     const float* __restrict__ wk, float* __restrict__ qn,
                     float* __restrict__ kn, int N) {
    __shared__ float sq[8 * 65], sk[8 * 65];
    int t = threadIdx.x;
    for (int idx = t; idx < 8 * 64; idx += blockDim.x) {
        int r = idx >> 6, i = idx & 63;
        sq[r * 65 + i] = wq[idx];
        sk[r * 65 + i] = wk[idx];
    }
    __syncthreads();
    int g = blockIdx.x * blockDim.x + t;
    if (g < N * 8) {
        int n = g >> 3, r = g & 7;
        const float* xp = xin + (size_t)n * 64;
        float qa = 0.f, ka = 0.f;
#pragma unroll
        for (int i = 0; i < 64; i++) {
            float xv = xp[i];
            qa += xv * sq[r * 65 + i];
            ka += xv * sk[r * 65 + i];
        }
        qn[g] = qa;
        kn[g] = ka;
    }
}

// ---------------- MFMA relation transform (split-bf16, fp32 out) ----------------
// xw[r][n][o] (fp32) = X[n][:] . W[r][:][o].
// Split precision: X = Xhi + Xlo, W = Whi + Wlo (bf16 each);
// acc = Xhi.Whi + Xhi.Wlo + Xlo.Whi  (residual ~2^-18 relative).
template <int OUT>
__global__ __launch_bounds__(256) void k_xw_mfma(
        const float* __restrict__ xin,
        const __hip_bfloat16* __restrict__ wthi, const __hip_bfloat16* __restrict__ wtlo,
        float* __restrict__ xw, int N) {
    using v8s = __attribute__((ext_vector_type(8))) short;
    using v4f = __attribute__((ext_vector_type(4))) float;
    int r = blockIdx.y;
    int wave = threadIdx.x >> 6;
    int lane = threadIdx.x & 63;
    int quad = lane >> 4;
    int l15 = lane & 15;
    int m0 = blockIdx.x * 64 + wave * 16;
    int node = m0 + l15;

    v8s ahi0 = {}, alo0 = {}, ahi1 = {}, alo1 = {};
    if (node < N) {
        const float* xrow = xin + (size_t)node * 64;
#pragma unroll
        for (int j = 0; j < 8; j++) {
            float f0 = xrow[quad * 8 + j];
            __hip_bfloat16 h0 = __float2bfloat16(f0);
            __hip_bfloat16 l0 = __float2bfloat16(f0 - __bfloat162float(h0));
            ahi0[j] = *(short*)&h0;
            alo0[j] = *(short*)&l0;
            float f1 = xrow[32 + quad * 8 + j];
            __hip_bfloat16 h1 = __float2bfloat16(f1);
            __hip_bfloat16 l1 = __float2bfloat16(f1 - __bfloat162float(h1));
            ahi1[j] = *(short*)&h1;
            alo1[j] = *(short*)&l1;
        }
    }
    const short* whr = (const short*)(wthi + (size_t)r * OUT * 64);
    const short* wlr = (const short*)(wtlo + (size_t)r * OUT * 64);
#pragma unroll
    for (int nt = 0; nt < OUT; nt += 16) {
        const short* wh = whr + (nt + l15) * 64;
        const short* wl = wlr + (nt + l15) * 64;
        v8s bh0 = *(const v8s*)(wh + quad * 8);
        v8s bh1 = *(const v8s*)(wh + 32 + quad * 8);
        v8s bl0 = *(const v8s*)(wl + quad * 8);
        v8s bl1 = *(const v8s*)(wl + 32 + quad * 8);
        v4f acc = {0.f, 0.f, 0.f, 0.f};
        acc = __builtin_amdgcn_mfma_f32_16x16x32_bf16(ahi0, bh0, acc, 0, 0, 0);
        acc = __builtin_amdgcn_mfma_f32_16x16x32_bf16(ahi1, bh1, acc, 0, 0, 0);
        acc = __builtin_amdgcn_mfma_f32_16x16x32_bf16(ahi0, bl0, acc, 0, 0, 0);
        acc = __builtin_amdgcn_mfma_f32_16x16x32_bf16(ahi1, bl1, acc, 0, 0, 0);
        acc = __builtin_amdgcn_mfma_f32_16x16x32_bf16(alo0, bh0, acc, 0, 0, 0);
        acc = __builtin_amdgcn_mfma_f32_16x16x32_bf16(alo1, bh1, acc, 0, 0, 0);
#pragma unroll
        for (int g = 0; g < 4; g++) {
            int nrow = m0 + quad * 4 + g;
            if (nrow < N)
                xw[((size_t)r * N + nrow) * OUT + nt + l15] = acc[g];
        }
    }
}

// ---------------- aggregation ----------------
// One wave per dst node. Single pass: exp(logit) without max-sub (logits are
// O(+-10); value-identical softmax).
// HAZARD NOTE (found R3/R4): __shfl must NOT live inside the `if (s < r1)`
// branch — on CDNA, ds_bpermute applies EXEC, and reading a source lane that
// is inactive at the shfl returns garbage/0. Chunks with <8 active lanes
// (degree<8 nodes) then read q=0 for rel >= active-count. All cross-lane ops
// here execute with the FULL wave active (loop bounds are wave-uniform).
template <int OUT, bool RELU>
__global__ void k_agg(const int* __restrict__ rowptr, const int* __restrict__ csr,
                      const float* __restrict__ qn, const float* __restrict__ kn,
                      const float* __restrict__ xw, const float* __restrict__ bias,
                      float* __restrict__ xout, int N) {
    int wid = (blockIdx.x * blockDim.x + threadIdx.x) >> 6;
    int lane = threadIdx.x & 63;
    if (wid >= N) return;
    int n = wid;
    int r0 = rowptr[n], r1 = rowptr[n + 1];

    // preload this node's 8 q values into lanes 0..7, broadcast via shfl
    float qv = (lane < 8) ? qn[n * 8 + lane] : 0.f;

    float denom = 0.f;
    float acc = 0.f;
    for (int base = r0; base < r1; base += 64) {
        int s = base + lane;
        // full-wave section: loads/extracts + the cross-lane broadcast
        int pk = (s < r1) ? csr[s] : 0;
        int src = pk & 0x1FFFF;
        int rel = pk >> 17;
        float q = __shfl(qv, rel, 64);  // exec = all 64 lanes here
        float tv = 0.f;
        if (s < r1) {
            float v = q + kn[src * 8 + rel];
            v = (v >= 0.f) ? v : 0.2f * v;
            tv = __expf(v);
        }
        float ts = tv;
#pragma unroll
        for (int off = 32; off > 0; off >>= 1) ts += __shfl_xor(ts, off, 64);
        denom += ts;
        int cnt = min(64, r1 - base);
        for (int j = 0; j < cnt; j++) {
            float tj = __shfl(tv, j, 64);
            int pkj = __shfl(pk, j, 64);
            int srcj = pkj & 0x1FFFF;
            int relj = pkj >> 17;
            const float* xp = xw + ((size_t)relj * N + srcj) * OUT;
            if (lane < OUT) acc += tj * xp[lane];
        }
    }

    if (lane < OUT) {
        float o = acc / (denom + 1e-16f) + bias[lane];
        if (RELU) o = fmaxf(o, 0.f);
        xout[(size_t)n * OUT + lane] = o;
    }
}

// ---------------- host launch ----------------

extern "C" void kernel_launch(void* const* d_in, const int* in_sizes, int n_in,
                              void* d_out, int out_size, void* d_ws, size_t ws_size,
                              hipStream_t stream) {
    const float* x   = (const float*)d_in[0];
    const int*   ei  = (const int*)d_in[1];
    const int*   et  = (const int*)d_in[2];
    const float* W0  = (const float*)d_in[3];
    const float* Q0  = (const float*)d_in[4];
    const float* K0  = (const float*)d_in[5];
    const float* b0  = (const float*)d_in[6];
    const float* W1  = (const float*)d_in[7];
    const float* Q1  = (const float*)d_in[8];
    const float* K1  = (const float*)d_in[9];
    const float* b1  = (const float*)d_in[10];
    float* out = (float*)d_out;

    const int N = in_sizes[0] / 64;
    const int E = in_sizes[2];
    const int* src = ei;
    const int* dst = ei + E;

    char* p = (char*)d_ws;
    auto alloc = [&](size_t bytes) -> void* {
        void* r = (void*)p;
        p += ((bytes + 255) / 256) * 256;
        return r;
    };
    int* rowptr   = (int*)alloc((size_t)(N + 1) * 4);
    int* cursor   = (int*)alloc((size_t)(N + 1) * 4);
    int* deg      = (int*)alloc((size_t)N * 4);
    int* partials = (int*)alloc(256 * 4);
    int* csr      = (int*)alloc((size_t)E * 4);
    float* wq     = (float*)alloc(8 * 64 * 4);
    float* wk     = (float*)alloc(8 * 64 * 4);
    float* qn     = (float*)alloc((size_t)N * 8 * 4);
    float* kn     = (float*)alloc((size_t)N * 8 * 4);
    __hip_bfloat16* wthi = (__hip_bfloat16*)alloc((size_t)8 * 64 * 64 * 2);
    __hip_bfloat16* wtlo = (__hip_bfloat16*)alloc((size_t)8 * 64 * 64 * 2);
    float* xw     = (float*)alloc((size_t)8 * N * 64 * 4);
    float* h      = (float*)alloc((size_t)N * 64 * 4);

    // --- CSR build (shared by both layers) ---
    hipMemsetAsync(deg, 0, (size_t)N * 4, stream);
    k_hist<<<(E + 255) / 256, 256, 0, stream>>>(dst, deg, E);
    int nb = (N + 2047) / 2048;
    k_scan_a<<<nb, 256, 0, stream>>>(deg, rowptr + 1, partials, N);
    k_scan_b<<<1, 64, 0, stream>>>(partials, nb);
    k_scan_c<<<(N + 255) / 256, 256, 0, stream>>>(rowptr, partials, N);
    hipMemcpyAsync(cursor, rowptr, (size_t)(N + 1) * 4, hipMemcpyDeviceToDevice, stream);
    k_scatter<<<(E + 255) / 256, 256, 0, stream>>>(src, dst, et, cursor, csr, E);

    int nxb = (N + 63) / 64;

    // --- layer 0: 64 -> 64, relu ---
    k_wqk<<<2, 256, 0, stream>>>(W0, Q0, K0, wq, wk, 64);
    k_qk<<<(N * 8 + 255) / 256, 256, 0, stream>>>(x, wq, wk, qn, kn, N);
    k_wt<<<(8 * 64 * 64 + 255) / 256, 256, 0, stream>>>(W0, wthi, wtlo, 64, 8 * 64 * 64);
    k_xw_mfma<64><<<dim3(nxb, 8), 256, 0, stream>>>(x, wthi, wtlo, xw, N);
    k_agg<64, true><<<(N * 64 + 255) / 256, 256, 0, stream>>>(rowptr, csr, qn, kn, xw, b0, h, N);

    // --- layer 1: 64 -> 32, no relu ---
    k_wqk<<<2, 256, 0, stream>>>(W1, Q1, K1, wq, wk, 32);
    k_qk<<<(N * 8 + 255) / 256, 256, 0, stream>>>(h, wq, wk, qn, kn, N);
    k_wt<<<(8 * 64 * 32 + 255) / 256, 256, 0, stream>>>(W1, wthi, wtlo, 32, 8 * 64 * 32);
    k_xw_mfma<32><<<dim3(nxb, 8), 256, 0, stream>>>(h, wthi, wtlo, xw, N);
    k_agg<32, false><<<(N * 64 + 255) / 256, 256, 0, stream>>>(rowptr, csr, qn, kn, xw, b1, out, N);
}

// Round 6
// 696.311 us; speedup vs baseline: 1.1568x; 1.0417x over previous
//
#include <hip/hip_runtime.h>
#include <hip/hip_bf16.h>
#include <math.h>

// ---------------- graph preprocessing ----------------

__global__ void k_hist(const int* dst, int* deg, int E) {
    int e = blockIdx.x * blockDim.x + threadIdx.x;
    if (e < E) atomicAdd(&deg[dst[e]], 1);
}

__global__ void k_scan_a(const int* deg, int* out1, int* partials, int N) {
    __shared__ int sd[256];
    int t = threadIdx.x;
    int base = blockIdx.x * 2048 + t * 8;
    int v[8];
    int s = 0;
#pragma unroll
    for (int j = 0; j < 8; j++) {
        int idx = base + j;
        int d = (idx < N) ? deg[idx] : 0;
        s += d;
        v[j] = s;
    }
    sd[t] = s;
    __syncthreads();
    for (int off = 1; off < 256; off <<= 1) {
        int add = (t >= off) ? sd[t - off] : 0;
        __syncthreads();
        sd[t] += add;
        __syncthreads();
    }
    int excl = sd[t] - s;
#pragma unroll
    for (int j = 0; j < 8; j++) {
        int idx = base + j;
        if (idx < N) out1[idx] = excl + v[j];
    }
    if (t == 255) partials[blockIdx.x] = sd[255];
}

__global__ void k_scan_b(int* partials, int nb) {
    if (threadIdx.x == 0 && blockIdx.x == 0) {
        int s = 0;
        for (int i = 0; i < nb; i++) { s += partials[i]; partials[i] = s; }
    }
}

__global__ void k_scan_c(int* rowptr, const int* partials, int N) {
    int i = blockIdx.x * blockDim.x + threadIdx.x;
    if (i == 0) rowptr[0] = 0;
    if (i < N) {
        int blk = i / 2048;
        if (blk > 0) rowptr[1 + i] += partials[blk - 1];
    }
}

// pack = (rel<<17) | src   (src < 2^17, rel < 8)
__global__ void k_scatter(const int* src, const int* dst, const int* et,
                          int* cursor, int* csr, int E) {
    int e = blockIdx.x * blockDim.x + threadIdx.x;
    if (e < E) {
        int d = dst[e];
        int slot = atomicAdd(&cursor[d], 1);
        csr[slot] = (et[e] << 17) | src[e];
    }
}

// ---------------- weight prep ----------------

// Split-transpose into GEMM-B layout with K = i*8 + r (matches z layout):
// wt[o][i*8+r] = bf16(W[r][i][o]); lo = bf16 residual. K=512 rows total.
__global__ void k_wt2(const float* __restrict__ W, __hip_bfloat16* __restrict__ hi,
                      __hip_bfloat16* __restrict__ lo, int OUT, int total) {
    int t = blockIdx.x * blockDim.x + threadIdx.x;
    if (t < total) {
        int per = 64 * OUT;
        int r = t / per;
        int rem = t % per;
        int i = rem / OUT;
        int o = rem % OUT;
        float v = W[t];
        __hip_bfloat16 h = __float2bfloat16(v);
        __hip_bfloat16 l = __float2bfloat16(v - __bfloat162float(h));
        size_t idx = (size_t)o * 512 + i * 8 + r;
        hi[idx] = h;
        lo[idx] = l;
    }
}

// wq[r*64+i] = sum_o W[r,i,o]*Qv[o]; wk likewise. (fp32, tiny)
__global__ void k_wqk(const float* W, const float* Qv, const float* Kv,
                      float* wq, float* wk, int OUT) {
    int t = blockIdx.x * blockDim.x + threadIdx.x;
    if (t < 8 * 64) {
        int r = t >> 6, i = t & 63;
        const float* wrow = W + ((size_t)r * 64 + i) * OUT;
        float a = 0.f, b = 0.f;
        for (int o = 0; o < OUT; o++) {
            float w = wrow[o];
            a += w * Qv[o];
            b += w * Kv[o];
        }
        wq[t] = a;
        wk[t] = b;
    }
}

// qn[n*8+r] = sum_i xin[n,i]*wq[r,i]; kn likewise. IN fixed at 64. (fp32)
__global__ void k_qk(const float* __restrict__ xin, const float* __restrict__ wq,
                     const float* __restrict__ wk, float* __restrict__ qn,
                     float* __restrict__ kn, int N) {
    __shared__ float sq[8 * 65], sk[8 * 65];
    int t = threadIdx.x;
    for (int idx = t; idx < 8 * 64; idx += blockDim.x) {
        int r = idx >> 6, i = idx & 63;
        sq[r * 65 + i] = wq[idx];
        sk[r * 65 + i] = wk[idx];
    }
    __syncthreads();
    int g = blockIdx.x * blockDim.x + t;
    if (g < N * 8) {
        int n = g >> 3, r = g & 7;
        const float* xp = xin + (size_t)n * 64;
        float qa = 0.f, ka = 0.f;
#pragma unroll
        for (int i = 0; i < 64; i++) {
            float xv = xp[i];
            qa += xv * sq[r * 65 + i];
            ka += xv * sk[r * 65 + i];
        }
        qn[g] = qa;
        kn[g] = ka;
    }
}

// ---------------- aggregation into per-relation z (bf16) ----------------
// One wave per dst node. Single-pass softmax (no max-sub; logits O(+-6)).
// z[n][ch*8 + r] = (1/denom) * sum_{e in rel r} exp(alpha_e) * xin[src_e][ch]
// Per-edge broadcast via v_readlane -> SGPRs (no bpermute in the hot loop);
// scalar src base -> saddr load of xin row; 8-way scalar switch on rel.
// HAZARD (R3/R4): all cross-lane ops run with the FULL wave active.
__global__ void k_agg2(const int* __restrict__ rowptr, const int* __restrict__ csr,
                       const float* __restrict__ qn, const float* __restrict__ kn,
                       const float* __restrict__ xin, __hip_bfloat16* __restrict__ z,
                       int N) {
    int wid = (blockIdx.x * blockDim.x + threadIdx.x) >> 6;
    int lane = threadIdx.x & 63;
    if (wid >= N) return;
    int r0 = rowptr[wid], r1 = rowptr[wid + 1];

    float qv = (lane < 8) ? qn[wid * 8 + lane] : 0.f;

    float denom = 0.f;
    float a0 = 0.f, a1 = 0.f, a2 = 0.f, a3 = 0.f;
    float a4 = 0.f, a5 = 0.f, a6 = 0.f, a7 = 0.f;

    for (int base = r0; base < r1; base += 64) {
        int s = base + lane;
        int pk = (s < r1) ? csr[s] : 0;
        int src = pk & 0x1FFFF;
        int rel = pk >> 17;
        float q = __shfl(qv, rel, 64);  // full wave active here
        float tv = 0.f;
        if (s < r1) {
            float v = q + kn[src * 8 + rel];
            v = (v >= 0.f) ? v : 0.2f * v;
            tv = __expf(v);
        }
        float ts = tv;
#pragma unroll
        for (int off = 32; off > 0; off >>= 1) ts += __shfl_xor(ts, off, 64);
        denom += ts;
        int cnt = min(64, r1 - base);
        for (int j = 0; j < cnt; j++) {
            unsigned pkj = (unsigned)__builtin_amdgcn_readlane(pk, j);
            float tj = __uint_as_float(
                (unsigned)__builtin_amdgcn_readlane((int)__float_as_uint(tv), j));
            int srcj = (int)(pkj & 0x1FFFF);
            int relj = (int)(pkj >> 17);
            float xv = xin[(size_t)srcj * 64 + lane];
            switch (relj) {
                case 0: a0 += tj * xv; break;
                case 1: a1 += tj * xv; break;
                case 2: a2 += tj * xv; break;
                case 3: a3 += tj * xv; break;
                case 4: a4 += tj * xv; break;
                case 5: a5 += tj * xv; break;
                case 6: a6 += tj * xv; break;
                case 7: a7 += tj * xv; break;
            }
        }
    }

    float inv = 1.f / (denom + 1e-16f);
    unsigned short u[8];
    float av[8] = {a0, a1, a2, a3, a4, a5, a6, a7};
#pragma unroll
    for (int r = 0; r < 8; r++) {
        __hip_bfloat16 b = __float2bfloat16(av[r] * inv);
        u[r] = *(unsigned short*)&b;
    }
    uint4 pack;
    pack.x = (unsigned)u[0] | ((unsigned)u[1] << 16);
    pack.y = (unsigned)u[2] | ((unsigned)u[3] << 16);
    pack.z = (unsigned)u[4] | ((unsigned)u[5] << 16);
    pack.w = (unsigned)u[6] | ((unsigned)u[7] << 16);
    *(uint4*)((unsigned short*)z + (size_t)wid * 512 + lane * 8) = pack;
}

// ---------------- final transform: out = z . Wcat (+bias, relu) ----------------
// GEMM M=N, K=512, N=OUT via mfma_f32_16x16x32_bf16.
// Wave covers 32 nodes (2 m-tiles), all OUT cols. W split hi/lo (z already bf16).
// A: lane holds z[m0+l15][k0+quad*8+j]; B: wt[(col)*512 + k0+quad*8+j].
// D: col=lane&15, row=quad*4+reg.
template <int OUT, bool RELU>
__global__ __launch_bounds__(256) void k_zw(
        const __hip_bfloat16* __restrict__ z,
        const __hip_bfloat16* __restrict__ wthi, const __hip_bfloat16* __restrict__ wtlo,
        const float* __restrict__ bias, float* __restrict__ xout, int N) {
    using v8s = __attribute__((ext_vector_type(8))) short;
    using v4f = __attribute__((ext_vector_type(4))) float;
    constexpr int NT = OUT / 16;
    int wave = threadIdx.x >> 6;
    int lane = threadIdx.x & 63;
    int quad = lane >> 4;
    int l15 = lane & 15;
    int m0 = (blockIdx.x * 4 + wave) * 32;
    if (m0 >= N) return;

    v4f acc[NT][2];
#pragma unroll
    for (int nt = 0; nt < NT; nt++) {
        acc[nt][0] = (v4f){0.f, 0.f, 0.f, 0.f};
        acc[nt][1] = (v4f){0.f, 0.f, 0.f, 0.f};
    }

    const short* zp = (const short*)z;
    const short* wh = (const short*)wthi;
    const short* wl = (const short*)wtlo;
    int n0 = m0 + l15, n1 = m0 + 16 + l15;

    for (int k0 = 0; k0 < 512; k0 += 32) {
        int koff = k0 + quad * 8;
        v8s A0 = {}, A1 = {};
        if (n0 < N) A0 = *(const v8s*)(zp + (size_t)n0 * 512 + koff);
        if (n1 < N) A1 = *(const v8s*)(zp + (size_t)n1 * 512 + koff);
#pragma unroll
        for (int nt = 0; nt < NT; nt++) {
            const short* bb = wh + (size_t)(nt * 16 + l15) * 512 + koff;
            const short* bb2 = wl + (size_t)(nt * 16 + l15) * 512 + koff;
            v8s bh = *(const v8s*)bb;
            v8s bl = *(const v8s*)bb2;
            acc[nt][0] = __builtin_amdgcn_mfma_f32_16x16x32_bf16(A0, bh, acc[nt][0], 0, 0, 0);
            acc[nt][0] = __builtin_amdgcn_mfma_f32_16x16x32_bf16(A0, bl, acc[nt][0], 0, 0, 0);
            acc[nt][1] = __builtin_amdgcn_mfma_f32_16x16x32_bf16(A1, bh, acc[nt][1], 0, 0, 0);
            acc[nt][1] = __builtin_amdgcn_mfma_f32_16x16x32_bf16(A1, bl, acc[nt][1], 0, 0, 0);
        }
    }

#pragma unroll
    for (int nt = 0; nt < NT; nt++) {
        float bcol = bias[nt * 16 + l15];
#pragma unroll
        for (int mm = 0; mm < 2; mm++) {
#pragma unroll
            for (int g = 0; g < 4; g++) {
                int row = m0 + mm * 16 + quad * 4 + g;
                if (row < N) {
                    float o = acc[nt][mm][g] + bcol;
                    if (RELU) o = fmaxf(o, 0.f);
                    xout[(size_t)row * OUT + nt * 16 + l15] = o;
                }
            }
        }
    }
}

// ---------------- host launch ----------------

extern "C" void kernel_launch(void* const* d_in, const int* in_sizes, int n_in,
                              void* d_out, int out_size, void* d_ws, size_t ws_size,
                              hipStream_t stream) {
    const float* x   = (const float*)d_in[0];
    const int*   ei  = (const int*)d_in[1];
    const int*   et  = (const int*)d_in[2];
    const float* W0  = (const float*)d_in[3];
    const float* Q0  = (const float*)d_in[4];
    const float* K0  = (const float*)d_in[5];
    const float* b0  = (const float*)d_in[6];
    const float* W1  = (const float*)d_in[7];
    const float* Q1  = (const float*)d_in[8];
    const float* K1  = (const float*)d_in[9];
    const float* b1  = (const float*)d_in[10];
    float* out = (float*)d_out;

    const int N = in_sizes[0] / 64;
    const int E = in_sizes[2];
    const int* src = ei;
    const int* dst = ei + E;

    char* p = (char*)d_ws;
    auto alloc = [&](size_t bytes) -> void* {
        void* r = (void*)p;
        p += ((bytes + 255) / 256) * 256;
        return r;
    };
    int* rowptr   = (int*)alloc((size_t)(N + 1) * 4);
    int* cursor   = (int*)alloc((size_t)(N + 1) * 4);
    int* deg      = (int*)alloc((size_t)N * 4);
    int* partials = (int*)alloc(256 * 4);
    int* csr      = (int*)alloc((size_t)E * 4);
    float* wq     = (float*)alloc(8 * 64 * 4);
    float* wk     = (float*)alloc(8 * 64 * 4);
    float* qn     = (float*)alloc((size_t)N * 8 * 4);
    float* kn     = (float*)alloc((size_t)N * 8 * 4);
    __hip_bfloat16* wthi = (__hip_bfloat16*)alloc((size_t)64 * 512 * 2);
    __hip_bfloat16* wtlo = (__hip_bfloat16*)alloc((size_t)64 * 512 * 2);
    __hip_bfloat16* z    = (__hip_bfloat16*)alloc((size_t)N * 512 * 2);
    float* h      = (float*)alloc((size_t)N * 64 * 4);

    // --- CSR build (shared by both layers) ---
    hipMemsetAsync(deg, 0, (size_t)N * 4, stream);
    k_hist<<<(E + 255) / 256, 256, 0, stream>>>(dst, deg, E);
    int nb = (N + 2047) / 2048;
    k_scan_a<<<nb, 256, 0, stream>>>(deg, rowptr + 1, partials, N);
    k_scan_b<<<1, 64, 0, stream>>>(partials, nb);
    k_scan_c<<<(N + 255) / 256, 256, 0, stream>>>(rowptr, partials, N);
    hipMemcpyAsync(cursor, rowptr, (size_t)(N + 1) * 4, hipMemcpyDeviceToDevice, stream);
    k_scatter<<<(E + 255) / 256, 256, 0, stream>>>(src, dst, et, cursor, csr, E);

    int naggb = (N * 64 + 255) / 256;
    int nzwb = (N + 127) / 128;

    // --- layer 0: 64 -> 64, relu ---
    k_wqk<<<2, 256, 0, stream>>>(W0, Q0, K0, wq, wk, 64);
    k_qk<<<(N * 8 + 255) / 256, 256, 0, stream>>>(x, wq, wk, qn, kn, N);
    k_wt2<<<(8 * 64 * 64 + 255) / 256, 256, 0, stream>>>(W0, wthi, wtlo, 64, 8 * 64 * 64);
    k_agg2<<<naggb, 256, 0, stream>>>(rowptr, csr, qn, kn, x, z, N);
    k_zw<64, true><<<nzwb, 256, 0, stream>>>(z, wthi, wtlo, b0, h, N);

    // --- layer 1: 64 -> 32, no relu ---
    k_wqk<<<2, 256, 0, stream>>>(W1, Q1, K1, wq, wk, 32);
    k_qk<<<(N * 8 + 255) / 256, 256, 0, stream>>>(h, wq, wk, qn, kn, N);
    k_wt2<<<(8 * 64 * 32 + 255) / 256, 256, 0, stream>>>(W1, wthi, wtlo, 32, 8 * 64 * 32);
    k_agg2<<<naggb, 256, 0, stream>>>(rowptr, csr, qn, kn, h, z, N);
    k_zw<32, false><<<nzwb, 256, 0, stream>>>(z, wthi, wtlo, b1, out, N);
}

// Round 7
// 574.478 us; speedup vs baseline: 1.4022x; 1.2121x over previous
//
#include <hip/hip_runtime.h>
#include <hip/hip_bf16.h>
#include <math.h>

// ---------------- bucketed CSR build ----------------
// bucket = dst >> 8 (256 nodes/bucket). NB = ceil(N/256) <= 512.
// R6 post-mortem: single-pass random 4B scatter into csr caused 16x write
// amplification (105 MB HBM writes for a 6.4 MB array). Two-level counting
// sort keeps every write either block-grouped (pass A) or inside a 16 KB
// L2-hot bucket window (pass B).

#define CSR_CHUNK 8192

__global__ void k_bhist(const int* __restrict__ dst, int* __restrict__ bcount,
                        int E, int NB) {
    __shared__ int h[512];
    int t = threadIdx.x;
    for (int i = t; i < NB; i += 256) h[i] = 0;
    __syncthreads();
    int e0 = blockIdx.x * CSR_CHUNK;
    int e1 = min(e0 + CSR_CHUNK, E);
    for (int i = e0 + t; i < e1; i += 256) atomicAdd(&h[dst[i] >> 8], 1);
    __syncthreads();
    for (int i = t; i < NB; i += 256) {
        int c = h[i];
        if (c) atomicAdd(&bcount[i], c);
    }
}

// single block, 512 threads: exclusive scan of bcount -> bstart (NB+1), copy
// to gcur (mutable cursors), and set rowptr[N] = E.
__global__ void k_bscan(const int* __restrict__ bcount, int* __restrict__ bstart,
                        int* __restrict__ gcur, int* __restrict__ rowptr,
                        int NB, int N, int E) {
    __shared__ int s[512];
    int t = threadIdx.x;
    int v = (t < NB) ? bcount[t] : 0;
    s[t] = v;
    __syncthreads();
    for (int off = 1; off < 512; off <<= 1) {
        int a = (t >= off) ? s[t - off] : 0;
        __syncthreads();
        s[t] += a;
        __syncthreads();
    }
    int excl = s[t] - v;
    if (t < NB) {
        bstart[t] = excl;
        gcur[t] = excl;
    }
    if (t == 0) {
        bstart[NB] = E;
        rowptr[N] = E;
    }
}

// pass A: scatter packed edges grouped by bucket per block.
// pack: dstlocal(8) << 20 | rel(3) << 17 | src(17)
__global__ void k_bscatter(const int* __restrict__ src, const int* __restrict__ dst,
                           const int* __restrict__ et, int* __restrict__ gcur,
                           unsigned* __restrict__ ebuf, int E, int NB) {
    __shared__ int h[512];
    __shared__ int basearr[512];
    int t = threadIdx.x;
    for (int i = t; i < NB; i += 256) h[i] = 0;
    __syncthreads();
    int e0 = blockIdx.x * CSR_CHUNK;
    int e1 = min(e0 + CSR_CHUNK, E);
    for (int i = e0 + t; i < e1; i += 256) atomicAdd(&h[dst[i] >> 8], 1);
    __syncthreads();
    for (int i = t; i < NB; i += 256) {
        int c = h[i];
        basearr[i] = c ? atomicAdd(&gcur[i], c) : 0;
        h[i] = 0;
    }
    __syncthreads();
    for (int i = e0 + t; i < e1; i += 256) {
        int d = dst[i];
        int b = d >> 8;
        int off = atomicAdd(&h[b], 1);
        ebuf[basearr[b] + off] =
            ((unsigned)(d & 255) << 20) | ((unsigned)et[i] << 17) | (unsigned)src[i];
    }
}

// pass B: one block per bucket. Per-node counts -> rowptr; scatter csr entries
// (rel<<17|src) into the bucket's contiguous window.
__global__ void k_bsort(const unsigned* __restrict__ ebuf, const int* __restrict__ bstart,
                        int* __restrict__ rowptr, int* __restrict__ csr, int N) {
    __shared__ int lh[256];
    __shared__ int ls[256];
    __shared__ int ss[256];
    int b = blockIdx.x, t = threadIdx.x;
    int e0 = bstart[b], e1 = bstart[b + 1];
    lh[t] = 0;
    __syncthreads();
    for (int i = e0 + t; i < e1; i += 256) atomicAdd(&lh[(ebuf[i] >> 20) & 255], 1);
    __syncthreads();
    int v = lh[t];
    ss[t] = v;
    __syncthreads();
    for (int off = 1; off < 256; off <<= 1) {
        int a = (t >= off) ? ss[t - off] : 0;
        __syncthreads();
        ss[t] += a;
        __syncthreads();
    }
    ls[t] = ss[t] - v;  // exclusive scan
    int node = b * 256 + t;
    if (node < N) rowptr[node] = e0 + ls[t];
    lh[t] = 0;
    __syncthreads();
    for (int i = e0 + t; i < e1; i += 256) {
        unsigned u = ebuf[i];
        int d = (u >> 20) & 255;
        int off = atomicAdd(&lh[d], 1);
        csr[e0 + ls[d] + off] = (int)(u & 0xFFFFF);
    }
}

// ---------------- weight prep ----------------

// Split-transpose into GEMM-B layout with K = i*8 + r (matches z layout):
// wt[o][i*8+r] = bf16(W[r][i][o]); lo = bf16 residual. K=512 rows total.
__global__ void k_wt2(const float* __restrict__ W, __hip_bfloat16* __restrict__ hi,
                      __hip_bfloat16* __restrict__ lo, int OUT, int total) {
    int t = blockIdx.x * blockDim.x + threadIdx.x;
    if (t < total) {
        int per = 64 * OUT;
        int r = t / per;
        int rem = t % per;
        int i = rem / OUT;
        int o = rem % OUT;
        float v = W[t];
        __hip_bfloat16 h = __float2bfloat16(v);
        __hip_bfloat16 l = __float2bfloat16(v - __bfloat162float(h));
        size_t idx = (size_t)o * 512 + i * 8 + r;
        hi[idx] = h;
        lo[idx] = l;
    }
}

// wq[r*64+i] = sum_o W[r,i,o]*Qv[o]; wk likewise. (fp32, tiny)
__global__ void k_wqk(const float* W, const float* Qv, const float* Kv,
                      float* wq, float* wk, int OUT) {
    int t = blockIdx.x * blockDim.x + threadIdx.x;
    if (t < 8 * 64) {
        int r = t >> 6, i = t & 63;
        const float* wrow = W + ((size_t)r * 64 + i) * OUT;
        float a = 0.f, b = 0.f;
        for (int o = 0; o < OUT; o++) {
            float w = wrow[o];
            a += w * Qv[o];
            b += w * Kv[o];
        }
        wq[t] = a;
        wk[t] = b;
    }
}

// qn[n*8+r] = sum_i xin[n,i]*wq[r,i]; kn likewise. IN fixed at 64. (fp32)
__global__ void k_qk(const float* __restrict__ xin, const float* __restrict__ wq,
                     const float* __restrict__ wk, float* __restrict__ qn,
                     float* __restrict__ kn, int N) {
    __shared__ float sq[8 * 65], sk[8 * 65];
    int t = threadIdx.x;
    for (int idx = t; idx < 8 * 64; idx += blockDim.x) {
        int r = idx >> 6, i = idx & 63;
        sq[r * 65 + i] = wq[idx];
        sk[r * 65 + i] = wk[idx];
    }
    __syncthreads();
    int g = blockIdx.x * blockDim.x + t;
    if (g < N * 8) {
        int n = g >> 3, r = g & 7;
        const float* xp = xin + (size_t)n * 64;
        float qa = 0.f, ka = 0.f;
#pragma unroll
        for (int i = 0; i < 64; i++) {
            float xv = xp[i];
            qa += xv * sq[r * 65 + i];
            ka += xv * sk[r * 65 + i];
        }
        qn[g] = qa;
        kn[g] = ka;
    }
}

// ---------------- aggregation into per-relation z (bf16) ----------------
// One wave per dst node. Single-pass softmax (no max-sub; logits O(+-6)).
// z[n][ch*8 + r] = (1/denom) * sum_{e in rel r} exp(alpha_e) * xin[src_e][ch]
// Per-edge broadcast via v_readlane -> SGPRs; scalar src base -> saddr load.
// HAZARD (R3/R4): all cross-lane ops run with the FULL wave active.
__global__ void k_agg2(const int* __restrict__ rowptr, const int* __restrict__ csr,
                       const float* __restrict__ qn, const float* __restrict__ kn,
                       const float* __restrict__ xin, __hip_bfloat16* __restrict__ z,
                       int N) {
    int wid = (blockIdx.x * blockDim.x + threadIdx.x) >> 6;
    int lane = threadIdx.x & 63;
    if (wid >= N) return;
    int r0 = rowptr[wid], r1 = rowptr[wid + 1];

    float qv = (lane < 8) ? qn[wid * 8 + lane] : 0.f;

    float denom = 0.f;
    float a0 = 0.f, a1 = 0.f, a2 = 0.f, a3 = 0.f;
    float a4 = 0.f, a5 = 0.f, a6 = 0.f, a7 = 0.f;

    for (int base = r0; base < r1; base += 64) {
        int s = base + lane;
        int pk = (s < r1) ? csr[s] : 0;
        int src = pk & 0x1FFFF;
        int rel = pk >> 17;
        float q = __shfl(qv, rel, 64);  // full wave active here
        float tv = 0.f;
        if (s < r1) {
            float v = q + kn[src * 8 + rel];
            v = (v >= 0.f) ? v : 0.2f * v;
            tv = __expf(v);
        }
        float ts = tv;
#pragma unroll
        for (int off = 32; off > 0; off >>= 1) ts += __shfl_xor(ts, off, 64);
        denom += ts;
        int cnt = min(64, r1 - base);
        for (int j = 0; j < cnt; j++) {
            unsigned pkj = (unsigned)__builtin_amdgcn_readlane(pk, j);
            float tj = __uint_as_float(
                (unsigned)__builtin_amdgcn_readlane((int)__float_as_uint(tv), j));
            int srcj = (int)(pkj & 0x1FFFF);
            int relj = (int)(pkj >> 17);
            float xv = xin[(size_t)srcj * 64 + lane];
            switch (relj) {
                case 0: a0 += tj * xv; break;
                case 1: a1 += tj * xv; break;
                case 2: a2 += tj * xv; break;
                case 3: a3 += tj * xv; break;
                case 4: a4 += tj * xv; break;
                case 5: a5 += tj * xv; break;
                case 6: a6 += tj * xv; break;
                case 7: a7 += tj * xv; break;
            }
        }
    }

    float inv = 1.f / (denom + 1e-16f);
    unsigned short u[8];
    float av[8] = {a0, a1, a2, a3, a4, a5, a6, a7};
#pragma unroll
    for (int r = 0; r < 8; r++) {
        __hip_bfloat16 b = __float2bfloat16(av[r] * inv);
        u[r] = *(unsigned short*)&b;
    }
    uint4 pack;
    pack.x = (unsigned)u[0] | ((unsigned)u[1] << 16);
    pack.y = (unsigned)u[2] | ((unsigned)u[3] << 16);
    pack.z = (unsigned)u[4] | ((unsigned)u[5] << 16);
    pack.w = (unsigned)u[6] | ((unsigned)u[7] << 16);
    *(uint4*)((unsigned short*)z + (size_t)wid * 512 + lane * 8) = pack;
}

// ---------------- final transform: out = z . Wcat (+bias, relu) ----------------
// GEMM M=N, K=512, N=OUT via mfma_f32_16x16x32_bf16.
template <int OUT, bool RELU>
__global__ __launch_bounds__(256) void k_zw(
        const __hip_bfloat16* __restrict__ z,
        const __hip_bfloat16* __restrict__ wthi, const __hip_bfloat16* __restrict__ wtlo,
        const float* __restrict__ bias, float* __restrict__ xout, int N) {
    using v8s = __attribute__((ext_vector_type(8))) short;
    using v4f = __attribute__((ext_vector_type(4))) float;
    constexpr int NT = OUT / 16;
    int wave = threadIdx.x >> 6;
    int lane = threadIdx.x & 63;
    int quad = lane >> 4;
    int l15 = lane & 15;
    int m0 = (blockIdx.x * 4 + wave) * 32;
    if (m0 >= N) return;

    v4f acc[NT][2];
#pragma unroll
    for (int nt = 0; nt < NT; nt++) {
        acc[nt][0] = (v4f){0.f, 0.f, 0.f, 0.f};
        acc[nt][1] = (v4f){0.f, 0.f, 0.f, 0.f};
    }

    const short* zp = (const short*)z;
    const short* wh = (const short*)wthi;
    const short* wl = (const short*)wtlo;
    int n0 = m0 + l15, n1 = m0 + 16 + l15;

    for (int k0 = 0; k0 < 512; k0 += 32) {
        int koff = k0 + quad * 8;
        v8s A0 = {}, A1 = {};
        if (n0 < N) A0 = *(const v8s*)(zp + (size_t)n0 * 512 + koff);
        if (n1 < N) A1 = *(const v8s*)(zp + (size_t)n1 * 512 + koff);
#pragma unroll
        for (int nt = 0; nt < NT; nt++) {
            v8s bh = *(const v8s*)(wh + (size_t)(nt * 16 + l15) * 512 + koff);
            v8s bl = *(const v8s*)(wl + (size_t)(nt * 16 + l15) * 512 + koff);
            acc[nt][0] = __builtin_amdgcn_mfma_f32_16x16x32_bf16(A0, bh, acc[nt][0], 0, 0, 0);
            acc[nt][0] = __builtin_amdgcn_mfma_f32_16x16x32_bf16(A0, bl, acc[nt][0], 0, 0, 0);
            acc[nt][1] = __builtin_amdgcn_mfma_f32_16x16x32_bf16(A1, bh, acc[nt][1], 0, 0, 0);
            acc[nt][1] = __builtin_amdgcn_mfma_f32_16x16x32_bf16(A1, bl, acc[nt][1], 0, 0, 0);
        }
    }

#pragma unroll
    for (int nt = 0; nt < NT; nt++) {
        float bcol = bias[nt * 16 + l15];
#pragma unroll
        for (int mm = 0; mm < 2; mm++) {
#pragma unroll
            for (int g = 0; g < 4; g++) {
                int row = m0 + mm * 16 + quad * 4 + g;
                if (row < N) {
                    float o = acc[nt][mm][g] + bcol;
                    if (RELU) o = fmaxf(o, 0.f);
                    xout[(size_t)row * OUT + nt * 16 + l15] = o;
                }
            }
        }
    }
}

// ---------------- host launch ----------------

extern "C" void kernel_launch(void* const* d_in, const int* in_sizes, int n_in,
                              void* d_out, int out_size, void* d_ws, size_t ws_size,
                              hipStream_t stream) {
    const float* x   = (const float*)d_in[0];
    const int*   ei  = (const int*)d_in[1];
    const int*   et  = (const int*)d_in[2];
    const float* W0  = (const float*)d_in[3];
    const float* Q0  = (const float*)d_in[4];
    const float* K0  = (const float*)d_in[5];
    const float* b0  = (const float*)d_in[6];
    const float* W1  = (const float*)d_in[7];
    const float* Q1  = (const float*)d_in[8];
    const float* K1  = (const float*)d_in[9];
    const float* b1  = (const float*)d_in[10];
    float* out = (float*)d_out;

    const int N = in_sizes[0] / 64;
    const int E = in_sizes[2];
    const int* src = ei;
    const int* dst = ei + E;
    const int NB = (N + 255) >> 8;  // <= 512

    char* p = (char*)d_ws;
    auto alloc = [&](size_t bytes) -> void* {
        void* r = (void*)p;
        p += ((bytes + 255) / 256) * 256;
        return r;
    };
    int* rowptr   = (int*)alloc((size_t)(N + 1) * 4);
    int* bcount   = (int*)alloc((size_t)NB * 4);
    int* bstart   = (int*)alloc((size_t)(NB + 1) * 4);
    int* gcur     = (int*)alloc((size_t)NB * 4);
    unsigned* ebuf = (unsigned*)alloc((size_t)E * 4);
    int* csr      = (int*)alloc((size_t)E * 4);
    float* wq     = (float*)alloc(8 * 64 * 4);
    float* wk     = (float*)alloc(8 * 64 * 4);
    float* qn     = (float*)alloc((size_t)N * 8 * 4);
    float* kn     = (float*)alloc((size_t)N * 8 * 4);
    __hip_bfloat16* wthi = (__hip_bfloat16*)alloc((size_t)64 * 512 * 2);
    __hip_bfloat16* wtlo = (__hip_bfloat16*)alloc((size_t)64 * 512 * 2);
    __hip_bfloat16* z    = (__hip_bfloat16*)alloc((size_t)N * 512 * 2);
    float* h      = (float*)alloc((size_t)N * 64 * 4);

    // --- CSR build (bucketed counting sort; shared by both layers) ---
    int nchunks = (E + CSR_CHUNK - 1) / CSR_CHUNK;
    hipMemsetAsync(bcount, 0, (size_t)NB * 4, stream);
    k_bhist<<<nchunks, 256, 0, stream>>>(dst, bcount, E, NB);
    k_bscan<<<1, 512, 0, stream>>>(bcount, bstart, gcur, rowptr, NB, N, E);
    k_bscatter<<<nchunks, 256, 0, stream>>>(src, dst, et, gcur, ebuf, E, NB);
    k_bsort<<<NB, 256, 0, stream>>>(ebuf, bstart, rowptr, csr, N);

    int naggb = (N * 64 + 255) / 256;
    int nzwb = (N + 127) / 128;

    // --- layer 0: 64 -> 64, relu ---
    k_wqk<<<2, 256, 0, stream>>>(W0, Q0, K0, wq, wk, 64);
    k_qk<<<(N * 8 + 255) / 256, 256, 0, stream>>>(x, wq, wk, qn, kn, N);
    k_wt2<<<(8 * 64 * 64 + 255) / 256, 256, 0, stream>>>(W0, wthi, wtlo, 64, 8 * 64 * 64);
    k_agg2<<<naggb, 256, 0, stream>>>(rowptr, csr, qn, kn, x, z, N);
    k_zw<64, true><<<nzwb, 256, 0, stream>>>(z, wthi, wtlo, b0, h, N);

    // --- layer 1: 64 -> 32, no relu ---
    k_wqk<<<2, 256, 0, stream>>>(W1, Q1, K1, wq, wk, 32);
    k_qk<<<(N * 8 + 255) / 256, 256, 0, stream>>>(h, wq, wk, qn, kn, N);
    k_wt2<<<(8 * 64 * 32 + 255) / 256, 256, 0, stream>>>(W1, wthi, wtlo, 32, 8 * 64 * 32);
    k_agg2<<<naggb, 256, 0, stream>>>(rowptr, csr, qn, kn, h, z, N);
    k_zw<32, false><<<nzwb, 256, 0, stream>>>(z, wthi, wtlo, b1, out, N);
}